// Round 5
// baseline (780.151 us; speedup 1.0000x reference)
//
#include <hip/hip_runtime.h>
#include <stdint.h>

// AdaptiveMixing on gfx950. Inputs/outputs fp32; internal bf16 + fp32 accum.
// R5: both big GEMMs drop LDS staging entirely in the K-loop: A and B MFMA
// fragments are loaded global->VGPR as per-lane 16B dwordx4 (quads cover full
// 64B lines), distance-1 ping-pong pipeline, ZERO barriers in the K-loop.
// Rationale: R4 counters showed gemm_out latency-bound (MfmaUtil 14.5%, HBM
// 25%, traffic already at floor) -> the vmcnt(0) barrier drain was the stall.

#define GQ 4
#define KQ 256
#define NP 32768
#define TOTAL_T 8192
#define MPAR 4096
#define INP 32
#define EIN 64
#define EOUT 64
#define BQT 3600
#define LN_EPS 1e-5f

typedef short s16x8 __attribute__((ext_vector_type(8)));
typedef float f32x4 __attribute__((ext_vector_type(4)));
typedef unsigned short u16;

__device__ __forceinline__ u16 f2bf(float f){
  union { float f; unsigned int u; } t; t.f = f;
  return (u16)((t.u + 0x7FFFu + ((t.u >> 16) & 1u)) >> 16);
}

// ---------------- cast query fp32 -> bf16 ----------------
__global__ __launch_bounds__(256) void cast_qr(const float* __restrict__ in,
                                               u16* __restrict__ out){
  int i = blockIdx.x * 256 + threadIdx.x;      // 4 elems per thread
  float4 f = *(const float4*)(in + 4 * (size_t)i);
  u16 v[4] = { f2bf(f.x), f2bf(f.y), f2bf(f.z), f2bf(f.w) };
  *(uint2*)(out + 4 * (size_t)i) = *(const uint2*)v;
}

// ---------------- transpose + cast (fp32 R x C -> bf16 C x R) ----------------
__global__ __launch_bounds__(256) void transpose_cast(const float* __restrict__ in,
                                                      u16* __restrict__ out,
                                                      int R, int C){
  __shared__ float tile[32][33];
  int c0 = blockIdx.x * 32, r0 = blockIdx.y * 32;
  int tx = threadIdx.x, ty = threadIdx.y;
  #pragma unroll
  for (int i = 0; i < 32; i += 8)
    tile[ty + i][tx] = in[(size_t)(r0 + ty + i) * C + (c0 + tx)];
  __syncthreads();
  #pragma unroll
  for (int i = 0; i < 32; i += 8)
    out[(size_t)(c0 + ty + i) * R + (r0 + tx)] = f2bf(tile[tx][ty + i]);
}

// ---------------- [A] params = query @ Wp + bp  (reg-direct, no K-loop LDS) --
__global__ __launch_bounds__(256, 2) void gemm_params(
    const u16* __restrict__ qrb,   // [3600][256] bf16
    const u16* __restrict__ WpT,   // [32768][256] bf16
    const float* __restrict__ bp,  // [32768] fp32
    u16* __restrict__ buf)         // [3600][32768] bf16
{
  __shared__ u16 C[128 * 136];     // epilogue stage only
  int n_base = blockIdx.x * 128;
  int m_base = blockIdx.y * 128;
  int t = threadIdx.x, wave = t >> 6, lane = t & 63, quad = lane >> 4, l15 = lane & 15;
  int mrow0 = (wave & 1) * 64, ncol0 = (wave >> 1) * 64;

  const u16* ap[4]; const u16* bpt[4];
  #pragma unroll
  for (int i = 0; i < 4; i++) {
    int ar = m_base + mrow0 + i * 16 + l15; ar = ar < BQT ? ar : (BQT - 1);
    ap[i] = qrb + (size_t)ar * KQ + quad * 8;
    int br = n_base + ncol0 + i * 16 + l15;
    bpt[i] = WpT + (size_t)br * KQ + quad * 8;
  }

  const f32x4 fz = {0.f, 0.f, 0.f, 0.f};
  f32x4 acc[4][4];
  #pragma unroll
  for (int i = 0; i < 4; i++)
    #pragma unroll
    for (int j = 0; j < 4; j++) acc[i][j] = fz;

  s16x8 a[2][4], b[2][4], an[2][4], bn[2][4];
  #pragma unroll
  for (int ks = 0; ks < 2; ks++)
    #pragma unroll
    for (int i = 0; i < 4; i++) {
      a[ks][i] = *(const s16x8*)(ap[i] + ks * 32);
      b[ks][i] = *(const s16x8*)(bpt[i] + ks * 32);
    }
  // K = 256 -> 4 chunks of 64, ping-pong unroll-by-2
  #pragma unroll
  for (int ko = 0; ko < 4; ko += 2) {
    int k1 = (ko + 1) * 64;
    int k2 = (ko + 2 < 4 ? ko + 2 : 3) * 64;
    #pragma unroll
    for (int ks = 0; ks < 2; ks++)
      #pragma unroll
      for (int i = 0; i < 4; i++) {
        an[ks][i] = *(const s16x8*)(ap[i] + k1 + ks * 32);
        bn[ks][i] = *(const s16x8*)(bpt[i] + k1 + ks * 32);
      }
    #pragma unroll
    for (int ks = 0; ks < 2; ks++)
      #pragma unroll
      for (int i = 0; i < 4; i++)
        #pragma unroll
        for (int j = 0; j < 4; j++)
          acc[i][j] = __builtin_amdgcn_mfma_f32_16x16x32_bf16(a[ks][i], b[ks][j], acc[i][j], 0, 0, 0);
    #pragma unroll
    for (int ks = 0; ks < 2; ks++)
      #pragma unroll
      for (int i = 0; i < 4; i++) {
        a[ks][i] = *(const s16x8*)(ap[i] + k2 + ks * 32);
        b[ks][i] = *(const s16x8*)(bpt[i] + k2 + ks * 32);
      }
    #pragma unroll
    for (int ks = 0; ks < 2; ks++)
      #pragma unroll
      for (int i = 0; i < 4; i++)
        #pragma unroll
        for (int j = 0; j < 4; j++)
          acc[i][j] = __builtin_amdgcn_mfma_f32_16x16x32_bf16(an[ks][i], bn[ks][j], acc[i][j], 0, 0, 0);
  }

  // acc (+bias) -> LDS (stride 136) -> coalesced 16B stores
  #pragma unroll
  for (int j = 0; j < 4; j++) {
    int cl = ncol0 + j * 16 + l15;
    float bias = bp[n_base + cl];
    #pragma unroll
    for (int i = 0; i < 4; i++) {
      int rl = mrow0 + i * 16 + quad * 4;
      #pragma unroll
      for (int r = 0; r < 4; r++)
        C[(rl + r) * 136 + cl] = f2bf(acc[i][j][r] + bias);
    }
  }
  __syncthreads();
  int c8 = (t & 15) * 8;
  #pragma unroll
  for (int it = 0; it < 8; it++) {
    int row = (t >> 4) + it * 16;
    int gr = m_base + row;
    s16x8 v = *(const s16x8*)(&C[row * 136 + c8]);
    if (gr < BQT)
      *(s16x8*)(&buf[(size_t)gr * NP + n_base + c8]) = v;
  }
}

// ---------------- [B] per-(n,g) fused mixing (unchanged) ------------
#define MTSW(o, c) ((c) ^ ((((o) >> 3) & 7) * 8))
__global__ __launch_bounds__(256) void mixer(
    const float* __restrict__ x,  // [3600][4][32][64] fp32
    u16* __restrict__ buf)        // [3600][32768] bf16: params in / hidden out
{
  __shared__ u16 MT[64][72];
  __shared__ u16 H1[64][40];
  __shared__ u16 O2[128][72];
  __shared__ float redS[4], redQ[4];

  int bid = blockIdx.x;
  int nl = bid >> 2, g = bid & 3;
  int t = threadIdx.x, wave = t >> 6, lane = t & 63, quad = lane >> 4, l15 = lane & 15;
  u16* slice = buf + (size_t)nl * NP + g * TOTAL_T;
  const float* xs = x + ((size_t)nl * GQ + g) * (INP * EIN);

  s16x8 sfrag[2];
  #pragma unroll
  for (int mt = 0; mt < 2; mt++) {
    int qp = (wave * 2 + mt) * 16 + l15;
    sfrag[mt] = *(const s16x8*)(slice + MPAR + qp * INP + quad * 8);
  }
  s16x8 xfrag[2][2];
  #pragma unroll
  for (int nt = 0; nt < 2; nt++)
    #pragma unroll
    for (int ks = 0; ks < 2; ks++) {
      const float* src = xs + (nt * 16 + l15) * EIN + ks * 32 + quad * 8;
      float4 f0 = *(const float4*)(src);
      float4 f1 = *(const float4*)(src + 4);
      s16x8 v;
      v[0] = (short)f2bf(f0.x); v[1] = (short)f2bf(f0.y);
      v[2] = (short)f2bf(f0.z); v[3] = (short)f2bf(f0.w);
      v[4] = (short)f2bf(f1.x); v[5] = (short)f2bf(f1.y);
      v[6] = (short)f2bf(f1.z); v[7] = (short)f2bf(f1.w);
      xfrag[nt][ks] = v;
    }

  #pragma unroll
  for (int i = 0; i < 2; i++) {
    int ch = t + i * 256;
    int c = ch >> 3, o0 = (ch & 7) * 8;
    s16x8 v = *(const s16x8*)(slice + c * EOUT + o0);
    #pragma unroll
    for (int jj = 0; jj < 8; jj++) MT[o0 + jj][MTSW(o0 + jj, c)] = (u16)v[jj];
  }
  __syncthreads();

  const f32x4 fz = {0.f, 0.f, 0.f, 0.f};
  f32x4 acc1[2]; acc1[0] = fz; acc1[1] = fz;
  #pragma unroll
  for (int ks = 0; ks < 2; ks++) {
    int o = wave * 16 + l15;
    s16x8 a = *(const s16x8*)(&MT[o][MTSW(o, ks * 32 + quad * 8)]);
    acc1[0] = __builtin_amdgcn_mfma_f32_16x16x32_bf16(a, xfrag[0][ks], acc1[0], 0, 0, 0);
    acc1[1] = __builtin_amdgcn_mfma_f32_16x16x32_bf16(a, xfrag[1][ks], acc1[1], 0, 0, 0);
  }
  float s = 0.f, sq = 0.f;
  #pragma unroll
  for (int nt = 0; nt < 2; nt++)
    #pragma unroll
    for (int r = 0; r < 4; r++) { float v = acc1[nt][r]; s += v; sq += v * v; }
  #pragma unroll
  for (int off = 32; off >= 1; off >>= 1) { s += __shfl_xor(s, off); sq += __shfl_xor(sq, off); }
  if (lane == 0) { redS[wave] = s; redQ[wave] = sq; }
  __syncthreads();
  {
    float S1 = redS[0] + redS[1] + redS[2] + redS[3];
    float Q1 = redQ[0] + redQ[1] + redQ[2] + redQ[3];
    float mean = S1 * (1.f / 2048.f);
    float var = fmaxf(Q1 * (1.f / 2048.f) - mean * mean, 0.f);
    float rstd = rsqrtf(var + LN_EPS);
    #pragma unroll
    for (int nt = 0; nt < 2; nt++)
      #pragma unroll
      for (int r = 0; r < 4; r++) {
        float v = (acc1[nt][r] - mean) * rstd;
        v = v > 0.f ? v : 0.f;
        H1[wave * 16 + quad * 4 + r][nt * 16 + l15] = f2bf(v);
      }
  }
  __syncthreads();

  f32x4 acc2[2][4];
  #pragma unroll
  for (int mt = 0; mt < 2; mt++)
    #pragma unroll
    for (int nt = 0; nt < 4; nt++) acc2[mt][nt] = fz;
  #pragma unroll
  for (int nt = 0; nt < 4; nt++) {
    s16x8 b = *(const s16x8*)(&H1[nt * 16 + l15][quad * 8]);
    acc2[0][nt] = __builtin_amdgcn_mfma_f32_16x16x32_bf16(sfrag[0], b, acc2[0][nt], 0, 0, 0);
    acc2[1][nt] = __builtin_amdgcn_mfma_f32_16x16x32_bf16(sfrag[1], b, acc2[1][nt], 0, 0, 0);
  }
  s = 0.f; sq = 0.f;
  #pragma unroll
  for (int mt = 0; mt < 2; mt++)
    #pragma unroll
    for (int nt = 0; nt < 4; nt++)
      #pragma unroll
      for (int r = 0; r < 4; r++) { float v = acc2[mt][nt][r]; s += v; sq += v * v; }
  #pragma unroll
  for (int off = 32; off >= 1; off >>= 1) { s += __shfl_xor(s, off); sq += __shfl_xor(sq, off); }
  if (lane == 0) { redS[wave] = s; redQ[wave] = sq; }
  __syncthreads();
  {
    float S2 = redS[0] + redS[1] + redS[2] + redS[3];
    float Q2 = redQ[0] + redQ[1] + redQ[2] + redQ[3];
    float mean = S2 * (1.f / 8192.f);
    float var = fmaxf(Q2 * (1.f / 8192.f) - mean * mean, 0.f);
    float rstd = rsqrtf(var + LN_EPS);
    #pragma unroll
    for (int mt = 0; mt < 2; mt++)
      #pragma unroll
      for (int nt = 0; nt < 4; nt++)
        #pragma unroll
        for (int r = 0; r < 4; r++) {
          float v = (acc2[mt][nt][r] - mean) * rstd;
          v = v > 0.f ? v : 0.f;
          O2[(wave * 2 + mt) * 16 + quad * 4 + r][nt * 16 + l15] = f2bf(v);
        }
  }
  __syncthreads();
  #pragma unroll
  for (int i = 0; i < 4; i++) {
    int ch = t + i * 256;
    int qp = ch >> 3, o0 = (ch & 7) * 8;
    s16x8 v = *(const s16x8*)(&O2[qp][o0]);
    *(s16x8*)(slice + qp * EOUT + o0) = v;
  }
}

// ---------------- [C] out partials = hidden @ Wo (reg-direct, split-K) ------
__global__ __launch_bounds__(256, 2) void gemm_out(
    const u16* __restrict__ hid,  // [3600][32768] bf16
    const u16* __restrict__ WoT,  // [256][32768] bf16
    float* __restrict__ part,     // [KS][3600][256] fp32
    int kslice)
{
  int n_base = blockIdx.x * 128;
  int m_base = blockIdx.y * 128;
  int ksl = blockIdx.z;
  int t = threadIdx.x, wave = t >> 6, lane = t & 63, quad = lane >> 4, l15 = lane & 15;
  int mrow0 = (wave & 1) * 64, ncol0 = (wave >> 1) * 64;

  const u16* ap[4]; const u16* bpt[4];
  #pragma unroll
  for (int i = 0; i < 4; i++) {
    int ar = m_base + mrow0 + i * 16 + l15; ar = ar < BQT ? ar : (BQT - 1);
    ap[i] = hid + (size_t)ar * NP + quad * 8;
    int br = n_base + ncol0 + i * 16 + l15;
    bpt[i] = WoT + (size_t)br * NP + quad * 8;
  }

  const f32x4 fz = {0.f, 0.f, 0.f, 0.f};
  f32x4 acc[4][4];
  #pragma unroll
  for (int i = 0; i < 4; i++)
    #pragma unroll
    for (int j = 0; j < 4; j++) acc[i][j] = fz;

  int kbase = ksl * kslice;
  int nko = kslice / 64;

  s16x8 a[2][4], b[2][4], an[2][4], bn[2][4];
  #pragma unroll
  for (int ks = 0; ks < 2; ks++)
    #pragma unroll
    for (int i = 0; i < 4; i++) {
      a[ks][i] = *(const s16x8*)(ap[i] + kbase + ks * 32);
      b[ks][i] = *(const s16x8*)(bpt[i] + kbase + ks * 32);
    }
  for (int ko = 0; ko < nko; ko += 2) {
    int k1 = kbase + (ko + 1) * 64;
    int k2 = kbase + (ko + 2 < nko ? ko + 2 : nko - 1) * 64;
    #pragma unroll
    for (int ks = 0; ks < 2; ks++)
      #pragma unroll
      for (int i = 0; i < 4; i++) {
        an[ks][i] = *(const s16x8*)(ap[i] + k1 + ks * 32);
        bn[ks][i] = *(const s16x8*)(bpt[i] + k1 + ks * 32);
      }
    #pragma unroll
    for (int ks = 0; ks < 2; ks++)
      #pragma unroll
      for (int i = 0; i < 4; i++)
        #pragma unroll
        for (int j = 0; j < 4; j++)
          acc[i][j] = __builtin_amdgcn_mfma_f32_16x16x32_bf16(a[ks][i], b[ks][j], acc[i][j], 0, 0, 0);
    #pragma unroll
    for (int ks = 0; ks < 2; ks++)
      #pragma unroll
      for (int i = 0; i < 4; i++) {
        a[ks][i] = *(const s16x8*)(ap[i] + k2 + ks * 32);
        b[ks][i] = *(const s16x8*)(bpt[i] + k2 + ks * 32);
      }
    #pragma unroll
    for (int ks = 0; ks < 2; ks++)
      #pragma unroll
      for (int i = 0; i < 4; i++)
        #pragma unroll
        for (int j = 0; j < 4; j++)
          acc[i][j] = __builtin_amdgcn_mfma_f32_16x16x32_bf16(an[ks][i], bn[ks][j], acc[i][j], 0, 0, 0);
  }
  #pragma unroll
  for (int j = 0; j < 4; j++) {
    int colg = n_base + ncol0 + j * 16 + l15;
    #pragma unroll
    for (int i = 0; i < 4; i++) {
      int row0 = m_base + mrow0 + i * 16 + quad * 4;
      #pragma unroll
      for (int r = 0; r < 4; r++)
        if (row0 + r < BQT)
          part[((size_t)ksl * BQT + row0 + r) * 256 + colg] = acc[i][j][r];
    }
  }
}

// ---------------- [R] reduce partials + bias + residual -> fp32 out --------
__global__ __launch_bounds__(256) void reduce_out(
    const float* __restrict__ part, const float* __restrict__ qr,
    const float* __restrict__ bo, float* __restrict__ out, int KS)
{
  int nl = blockIdx.x, j = threadIdx.x;
  float s = bo[j] + qr[(size_t)nl * KQ + j];
  for (int ks = 0; ks < KS; ks++)
    s += part[((size_t)ks * BQT + nl) * 256 + j];
  out[(size_t)nl * KQ + j] = s;
}

extern "C" void kernel_launch(void* const* d_in, const int* in_sizes, int n_in,
                              void* d_out, int out_size, void* d_ws, size_t ws_size,
                              hipStream_t stream)
{
  (void)in_sizes; (void)n_in; (void)out_size;
  const float* x  = (const float*)d_in[0];
  const float* qr = (const float*)d_in[1];
  const float* Wp = (const float*)d_in[2];
  const float* bp = (const float*)d_in[3];
  const float* Wo = (const float*)d_in[4];
  const float* bo = (const float*)d_in[5];
  float* out = (float*)d_out;

  char* ws = (char*)d_ws;
  u16* WpT = (u16*)ws;                          // 16 MiB
  u16* WoT = (u16*)(ws + 16777216);             // 16 MiB
  u16* buf = (u16*)(ws + 33554432);             // 3600*32768*2 = 225 MiB
  char* tail = ws + 33554432ull + (size_t)BQT * NP * 2ull;
  u16* qrb  = (u16*)tail;                       // 1.8 MB (dead after gemm_params)
  float* part = (float*)tail;                   // aliased: KS*3600*256*4

  size_t base = 33554432ull + (size_t)BQT * NP * 2ull;
  int KS = (ws_size >= base + 16ull * BQT * 256 * 4) ? 16 : 8;
  int kslice = NP / KS;

  cast_qr<<<dim3(BQT * KQ / 1024), 256, 0, stream>>>(qr, qrb);
  transpose_cast<<<dim3(NP / 32, KQ / 32), dim3(32, 8), 0, stream>>>(Wp, WpT, KQ, NP);
  transpose_cast<<<dim3(KQ / 32, NP / 32), dim3(32, 8), 0, stream>>>(Wo, WoT, NP, KQ);

  gemm_params<<<dim3(NP / 128, 29), 256, 0, stream>>>(qrb, WpT, bp, buf);
  mixer<<<dim3(BQT * GQ), 256, 0, stream>>>(x, buf);
  gemm_out<<<dim3(2, 29, KS), 256, 0, stream>>>(buf, WoT, part, kslice);
  reduce_out<<<dim3(BQT), 256, 0, stream>>>(part, qr, bo, out, KS);
}

// Round 6
// 571.749 us; speedup vs baseline: 1.3645x; 1.3645x over previous
//
#include <hip/hip_runtime.h>
#include <stdint.h>

// AdaptiveMixing on gfx950. Inputs/outputs fp32; internal bf16 + fp32 accum.
// R6: revert to R4 structure (global_load_lds K-loops — R5's reg-direct
// pipeline collapsed: VALUBusy 3.6%, compiler serialized the waits).
// gemm_out M-tile 128->64: grid 464->912 blocks fixes the grid-limited
// occupancy (19%) that made R4's gemm_out latency-bound.

#define GQ 4
#define KQ 256
#define NP 32768
#define TOTAL_T 8192
#define MPAR 4096
#define INP 32
#define EIN 64
#define EOUT 64
#define BQT 3600
#define LN_EPS 1e-5f

typedef short s16x8 __attribute__((ext_vector_type(8)));
typedef float f32x4 __attribute__((ext_vector_type(4)));
typedef unsigned short u16;

__device__ __forceinline__ u16 f2bf(float f){
  union { float f; unsigned int u; } t; t.f = f;
  return (u16)((t.u + 0x7FFFu + ((t.u >> 16) & 1u)) >> 16);
}

// async global->LDS, 16 B per lane; lds base must be wave-uniform (HW adds lane*16)
__device__ __forceinline__ void gl16(const u16* g, u16* l){
  __builtin_amdgcn_global_load_lds(
      (const __attribute__((address_space(1))) unsigned int*)g,
      (__attribute__((address_space(3))) unsigned int*)l, 16, 0, 0);
}

// ---------------- cast query fp32 -> bf16 ----------------
__global__ __launch_bounds__(256) void cast_qr(const float* __restrict__ in,
                                               u16* __restrict__ out){
  int i = blockIdx.x * 256 + threadIdx.x;      // 4 elems per thread
  float4 f = *(const float4*)(in + 4 * (size_t)i);
  u16 v[4] = { f2bf(f.x), f2bf(f.y), f2bf(f.z), f2bf(f.w) };
  *(uint2*)(out + 4 * (size_t)i) = *(const uint2*)v;
}

// ---------------- transpose + cast (fp32 R x C -> bf16 C x R) ----------------
__global__ __launch_bounds__(256) void transpose_cast(const float* __restrict__ in,
                                                      u16* __restrict__ out,
                                                      int R, int C){
  __shared__ float tile[32][33];
  int c0 = blockIdx.x * 32, r0 = blockIdx.y * 32;
  int tx = threadIdx.x, ty = threadIdx.y;
  #pragma unroll
  for (int i = 0; i < 32; i += 8)
    tile[ty + i][tx] = in[(size_t)(r0 + ty + i) * C + (c0 + tx)];
  __syncthreads();
  #pragma unroll
  for (int i = 0; i < 32; i += 8)
    out[(size_t)(c0 + ty + i) * R + (r0 + tx)] = f2bf(tile[tx][ty + i]);
}

// ---------------- [A] params = query @ Wp + bp  (m97-style 128x128) ---------
// Epilogue: acc -> LDS (stride 136, bank-friendly) -> coalesced 16B stores.
__global__ __launch_bounds__(256) void gemm_params(
    const u16* __restrict__ qrb,   // [3600][256] bf16
    const u16* __restrict__ WpT,   // [32768][256] bf16
    const float* __restrict__ bp,  // [32768] fp32
    u16* __restrict__ buf)         // [3600][32768] bf16
{
  __shared__ union SM {
    u16 AB[16384];     // As = [0,8192), Bs = [8192,16384)
    u16 C[128 * 136];  // epilogue stage (alias; used after final barrier)
  } sm;
  u16* As = sm.AB;
  u16* Bs = sm.AB + 8192;

  int n_base = blockIdx.x * 128;
  int m_base = blockIdx.y * 128;
  int t = threadIdx.x, wave = t >> 6, lane = t & 63, quad = lane >> 4, l15 = lane & 15;
  int mrow0 = (wave & 1) * 64, ncol0 = (wave >> 1) * 64;
  int srow = wave * 8 + (lane >> 3);      // staging row within 32-row band
  int scol = (lane & 7) * 8;              // staging col (k)

  const f32x4 fz = {0.f, 0.f, 0.f, 0.f};
  f32x4 acc[4][4];
  #pragma unroll
  for (int i = 0; i < 4; i++)
    #pragma unroll
    for (int j = 0; j < 4; j++) acc[i][j] = fz;

  for (int ko = 0; ko < 4; ko++) {
    int k0 = ko * 64;
    #pragma unroll
    for (int i = 0; i < 4; i++) {
      int ar = m_base + i * 32 + srow; ar = ar < (BQT - 1) ? ar : (BQT - 1);
      gl16(qrb + (size_t)ar * KQ + k0 + scol, As + i * 2048 + wave * 512);
      int br = n_base + i * 32 + srow;
      gl16(WpT + (size_t)br * KQ + k0 + scol, Bs + i * 2048 + wave * 512);
    }
    __syncthreads();
    #pragma unroll
    for (int ks = 0; ks < 2; ks++) {
      s16x8 a[4], b[4];
      #pragma unroll
      for (int i = 0; i < 4; i++)
        a[i] = *(const s16x8*)(As + (mrow0 + i * 16 + l15) * 64 + ks * 32 + quad * 8);
      #pragma unroll
      for (int j = 0; j < 4; j++)
        b[j] = *(const s16x8*)(Bs + (ncol0 + j * 16 + l15) * 64 + ks * 32 + quad * 8);
      #pragma unroll
      for (int i = 0; i < 4; i++)
        #pragma unroll
        for (int j = 0; j < 4; j++)
          acc[i][j] = __builtin_amdgcn_mfma_f32_16x16x32_bf16(a[i], b[j], acc[i][j], 0, 0, 0);
    }
    __syncthreads();
  }

  // acc (+bias) -> LDS, bf16, row stride 136 (bank shift 4/row: conflict-free)
  #pragma unroll
  for (int j = 0; j < 4; j++) {
    int cl = ncol0 + j * 16 + l15;
    float bias = bp[n_base + cl];
    #pragma unroll
    for (int i = 0; i < 4; i++) {
      int rl = mrow0 + i * 16 + quad * 4;
      #pragma unroll
      for (int r = 0; r < 4; r++)
        sm.C[(rl + r) * 136 + cl] = f2bf(acc[i][j][r] + bias);
    }
  }
  __syncthreads();
  // coalesced stores: lanes 0..15 cover one 256B row; wave = 4 full rows/instr
  int c8 = (t & 15) * 8;
  #pragma unroll
  for (int it = 0; it < 8; it++) {
    int row = (t >> 4) + it * 16;
    int gr = m_base + row;
    s16x8 v = *(const s16x8*)(&sm.C[row * 136 + c8]);
    if (gr < BQT)
      *(s16x8*)(&buf[(size_t)gr * NP + n_base + c8]) = v;
  }
}

// ---------------- [B] per-(n,g) fused mixing (unchanged) ------------
#define MTSW(o, c) ((c) ^ ((((o) >> 3) & 7) * 8))
__global__ __launch_bounds__(256) void mixer(
    const float* __restrict__ x,  // [3600][4][32][64] fp32
    u16* __restrict__ buf)        // [3600][32768] bf16: params in / hidden out
{
  __shared__ u16 MT[64][72];
  __shared__ u16 H1[64][40];
  __shared__ u16 O2[128][72];
  __shared__ float redS[4], redQ[4];

  int bid = blockIdx.x;
  int nl = bid >> 2, g = bid & 3;
  int t = threadIdx.x, wave = t >> 6, lane = t & 63, quad = lane >> 4, l15 = lane & 15;
  u16* slice = buf + (size_t)nl * NP + g * TOTAL_T;
  const float* xs = x + ((size_t)nl * GQ + g) * (INP * EIN);

  s16x8 sfrag[2];
  #pragma unroll
  for (int mt = 0; mt < 2; mt++) {
    int qp = (wave * 2 + mt) * 16 + l15;
    sfrag[mt] = *(const s16x8*)(slice + MPAR + qp * INP + quad * 8);
  }
  s16x8 xfrag[2][2];
  #pragma unroll
  for (int nt = 0; nt < 2; nt++)
    #pragma unroll
    for (int ks = 0; ks < 2; ks++) {
      const float* src = xs + (nt * 16 + l15) * EIN + ks * 32 + quad * 8;
      float4 f0 = *(const float4*)(src);
      float4 f1 = *(const float4*)(src + 4);
      s16x8 v;
      v[0] = (short)f2bf(f0.x); v[1] = (short)f2bf(f0.y);
      v[2] = (short)f2bf(f0.z); v[3] = (short)f2bf(f0.w);
      v[4] = (short)f2bf(f1.x); v[5] = (short)f2bf(f1.y);
      v[6] = (short)f2bf(f1.z); v[7] = (short)f2bf(f1.w);
      xfrag[nt][ks] = v;
    }

  #pragma unroll
  for (int i = 0; i < 2; i++) {
    int ch = t + i * 256;
    int c = ch >> 3, o0 = (ch & 7) * 8;
    s16x8 v = *(const s16x8*)(slice + c * EOUT + o0);
    #pragma unroll
    for (int jj = 0; jj < 8; jj++) MT[o0 + jj][MTSW(o0 + jj, c)] = (u16)v[jj];
  }
  __syncthreads();

  const f32x4 fz = {0.f, 0.f, 0.f, 0.f};
  f32x4 acc1[2]; acc1[0] = fz; acc1[1] = fz;
  #pragma unroll
  for (int ks = 0; ks < 2; ks++) {
    int o = wave * 16 + l15;
    s16x8 a = *(const s16x8*)(&MT[o][MTSW(o, ks * 32 + quad * 8)]);
    acc1[0] = __builtin_amdgcn_mfma_f32_16x16x32_bf16(a, xfrag[0][ks], acc1[0], 0, 0, 0);
    acc1[1] = __builtin_amdgcn_mfma_f32_16x16x32_bf16(a, xfrag[1][ks], acc1[1], 0, 0, 0);
  }
  float s = 0.f, sq = 0.f;
  #pragma unroll
  for (int nt = 0; nt < 2; nt++)
    #pragma unroll
    for (int r = 0; r < 4; r++) { float v = acc1[nt][r]; s += v; sq += v * v; }
  #pragma unroll
  for (int off = 32; off >= 1; off >>= 1) { s += __shfl_xor(s, off); sq += __shfl_xor(sq, off); }
  if (lane == 0) { redS[wave] = s; redQ[wave] = sq; }
  __syncthreads();
  {
    float S1 = redS[0] + redS[1] + redS[2] + redS[3];
    float Q1 = redQ[0] + redQ[1] + redQ[2] + redQ[3];
    float mean = S1 * (1.f / 2048.f);
    float var = fmaxf(Q1 * (1.f / 2048.f) - mean * mean, 0.f);
    float rstd = rsqrtf(var + LN_EPS);
    #pragma unroll
    for (int nt = 0; nt < 2; nt++)
      #pragma unroll
      for (int r = 0; r < 4; r++) {
        float v = (acc1[nt][r] - mean) * rstd;
        v = v > 0.f ? v : 0.f;
        H1[wave * 16 + quad * 4 + r][nt * 16 + l15] = f2bf(v);
      }
  }
  __syncthreads();

  f32x4 acc2[2][4];
  #pragma unroll
  for (int mt = 0; mt < 2; mt++)
    #pragma unroll
    for (int nt = 0; nt < 4; nt++) acc2[mt][nt] = fz;
  #pragma unroll
  for (int nt = 0; nt < 4; nt++) {
    s16x8 b = *(const s16x8*)(&H1[nt * 16 + l15][quad * 8]);
    acc2[0][nt] = __builtin_amdgcn_mfma_f32_16x16x32_bf16(sfrag[0], b, acc2[0][nt], 0, 0, 0);
    acc2[1][nt] = __builtin_amdgcn_mfma_f32_16x16x32_bf16(sfrag[1], b, acc2[1][nt], 0, 0, 0);
  }
  s = 0.f; sq = 0.f;
  #pragma unroll
  for (int mt = 0; mt < 2; mt++)
    #pragma unroll
    for (int nt = 0; nt < 4; nt++)
      #pragma unroll
      for (int r = 0; r < 4; r++) { float v = acc2[mt][nt][r]; s += v; sq += v * v; }
  #pragma unroll
  for (int off = 32; off >= 1; off >>= 1) { s += __shfl_xor(s, off); sq += __shfl_xor(sq, off); }
  if (lane == 0) { redS[wave] = s; redQ[wave] = sq; }
  __syncthreads();
  {
    float S2 = redS[0] + redS[1] + redS[2] + redS[3];
    float Q2 = redQ[0] + redQ[1] + redQ[2] + redQ[3];
    float mean = S2 * (1.f / 8192.f);
    float var = fmaxf(Q2 * (1.f / 8192.f) - mean * mean, 0.f);
    float rstd = rsqrtf(var + LN_EPS);
    #pragma unroll
    for (int mt = 0; mt < 2; mt++)
      #pragma unroll
      for (int nt = 0; nt < 4; nt++)
        #pragma unroll
        for (int r = 0; r < 4; r++) {
          float v = (acc2[mt][nt][r] - mean) * rstd;
          v = v > 0.f ? v : 0.f;
          O2[(wave * 2 + mt) * 16 + quad * 4 + r][nt * 16 + l15] = f2bf(v);
        }
  }
  __syncthreads();
  #pragma unroll
  for (int i = 0; i < 4; i++) {
    int ch = t + i * 256;
    int qp = ch >> 3, o0 = (ch & 7) * 8;
    s16x8 v = *(const s16x8*)(&O2[qp][o0]);
    *(s16x8*)(slice + qp * EOUT + o0) = v;
  }
}

// ---------------- [C] out partials = hidden @ Wo (64x128 tile, split-K) -----
// M-tile 64 doubles the grid (912 blocks) vs R4 -> fixes grid-limited occupancy.
__global__ __launch_bounds__(256) void gemm_out(
    const u16* __restrict__ hid,  // [3600][32768] bf16
    const u16* __restrict__ WoT,  // [256][32768] bf16
    float* __restrict__ part,     // [KS][3600][256] fp32
    int kslice)                   // K per split slice
{
  __shared__ u16 As[64 * 64];     // 8 KB
  __shared__ u16 Bs[128 * 64];    // 16 KB
  int n_base = blockIdx.x * 128;
  int m_base = blockIdx.y * 64;
  int ksl = blockIdx.z;
  int t = threadIdx.x, wave = t >> 6, lane = t & 63, quad = lane >> 4, l15 = lane & 15;
  int mrow0 = (wave & 1) * 32, ncol0 = (wave >> 1) * 64;
  int srow = wave * 8 + (lane >> 3);
  int scol = (lane & 7) * 8;

  const f32x4 fz = {0.f, 0.f, 0.f, 0.f};
  f32x4 acc[2][4];
  #pragma unroll
  for (int i = 0; i < 2; i++)
    #pragma unroll
    for (int j = 0; j < 4; j++) acc[i][j] = fz;

  int kbase = ksl * kslice;
  for (int ko = 0; ko < kslice / 64; ko++) {
    int k0 = kbase + ko * 64;
    #pragma unroll
    for (int i = 0; i < 2; i++) {
      int ar = m_base + i * 32 + srow; ar = ar < (BQT - 1) ? ar : (BQT - 1);
      gl16(hid + (size_t)ar * NP + k0 + scol, As + i * 2048 + wave * 512);
    }
    #pragma unroll
    for (int i = 0; i < 4; i++) {
      int br = n_base + i * 32 + srow;
      gl16(WoT + (size_t)br * NP + k0 + scol, Bs + i * 2048 + wave * 512);
    }
    __syncthreads();
    #pragma unroll
    for (int ks = 0; ks < 2; ks++) {
      s16x8 a[2], b[4];
      #pragma unroll
      for (int i = 0; i < 2; i++)
        a[i] = *(const s16x8*)(As + (mrow0 + i * 16 + l15) * 64 + ks * 32 + quad * 8);
      #pragma unroll
      for (int j = 0; j < 4; j++)
        b[j] = *(const s16x8*)(Bs + (ncol0 + j * 16 + l15) * 64 + ks * 32 + quad * 8);
      #pragma unroll
      for (int i = 0; i < 2; i++)
        #pragma unroll
        for (int j = 0; j < 4; j++)
          acc[i][j] = __builtin_amdgcn_mfma_f32_16x16x32_bf16(a[i], b[j], acc[i][j], 0, 0, 0);
    }
    __syncthreads();
  }
  #pragma unroll
  for (int j = 0; j < 4; j++) {
    int colg = n_base + ncol0 + j * 16 + l15;
    #pragma unroll
    for (int i = 0; i < 2; i++) {
      int row0 = m_base + mrow0 + i * 16 + quad * 4;
      #pragma unroll
      for (int r = 0; r < 4; r++)
        if (row0 + r < BQT)
          part[((size_t)ksl * BQT + row0 + r) * 256 + colg] = acc[i][j][r];
    }
  }
}

// ---------------- [R] reduce partials + bias + residual -> fp32 out --------
__global__ __launch_bounds__(256) void reduce_out(
    const float* __restrict__ part, const float* __restrict__ qr,
    const float* __restrict__ bo, float* __restrict__ out, int KS)
{
  int nl = blockIdx.x, j = threadIdx.x;
  float s = bo[j] + qr[(size_t)nl * KQ + j];
  for (int ks = 0; ks < KS; ks++)
    s += part[((size_t)ks * BQT + nl) * 256 + j];
  out[(size_t)nl * KQ + j] = s;
}

extern "C" void kernel_launch(void* const* d_in, const int* in_sizes, int n_in,
                              void* d_out, int out_size, void* d_ws, size_t ws_size,
                              hipStream_t stream)
{
  (void)in_sizes; (void)n_in; (void)out_size;
  const float* x  = (const float*)d_in[0];
  const float* qr = (const float*)d_in[1];
  const float* Wp = (const float*)d_in[2];
  const float* bp = (const float*)d_in[3];
  const float* Wo = (const float*)d_in[4];
  const float* bo = (const float*)d_in[5];
  float* out = (float*)d_out;

  char* ws = (char*)d_ws;
  u16* WpT = (u16*)ws;                          // 16 MiB
  u16* WoT = (u16*)(ws + 16777216);             // 16 MiB
  u16* buf = (u16*)(ws + 33554432);             // 3600*32768*2 = 225 MiB
  char* tail = ws + 33554432ull + (size_t)BQT * NP * 2ull;
  u16* qrb  = (u16*)tail;                       // 1.8 MB (dead after gemm_params)
  float* part = (float*)tail;                   // aliased: KS*3600*256*4

  size_t base = 33554432ull + (size_t)BQT * NP * 2ull;
  int KS = (ws_size >= base + 16ull * BQT * 256 * 4) ? 16 : 8;
  int kslice = NP / KS;

  cast_qr<<<dim3(BQT * KQ / 1024), 256, 0, stream>>>(qr, qrb);
  transpose_cast<<<dim3(NP / 32, KQ / 32), dim3(32, 8), 0, stream>>>(Wp, WpT, KQ, NP);
  transpose_cast<<<dim3(KQ / 32, NP / 32), dim3(32, 8), 0, stream>>>(Wo, WoT, NP, KQ);

  gemm_params<<<dim3(NP / 128, 29), 256, 0, stream>>>(qrb, WpT, bp, buf);
  mixer<<<dim3(BQT * GQ), 256, 0, stream>>>(x, buf);
  gemm_out<<<dim3(2, 57, KS), 256, 0, stream>>>(buf, WoT, part, kslice);
  reduce_out<<<dim3(BQT), 256, 0, stream>>>(part, qr, bo, out, KS);
}

// Round 7
// 559.396 us; speedup vs baseline: 1.3946x; 1.0221x over previous
//
#include <hip/hip_runtime.h>
#include <stdint.h>

// AdaptiveMixing on gfx950. Inputs/outputs fp32; internal bf16 + fp32 accum.
// R7: XOR-swizzled LDS staging in both GEMMs. R6 counters: 3.36e7 LDS bank
// conflict cycles (~33% of gemm_out) because row-major [row][k] stride-128B
// puts every quad's 16 lanes on the same 4-bank group. Lane now FETCHES chunk
// (lane&7)^(srow&7) so physical slot s of row r holds chunk s^(r&7); reads
// use swz = (quad^(l15&7))*8 (ks=1: ^32). Quad lanes now spread across all
// 32 banks (2-way = free).

#define GQ 4
#define KQ 256
#define NP 32768
#define TOTAL_T 8192
#define MPAR 4096
#define INP 32
#define EIN 64
#define EOUT 64
#define BQT 3600
#define LN_EPS 1e-5f

typedef short s16x8 __attribute__((ext_vector_type(8)));
typedef float f32x4 __attribute__((ext_vector_type(4)));
typedef unsigned short u16;

__device__ __forceinline__ u16 f2bf(float f){
  union { float f; unsigned int u; } t; t.f = f;
  return (u16)((t.u + 0x7FFFu + ((t.u >> 16) & 1u)) >> 16);
}

// async global->LDS, 16 B per lane; lds base must be wave-uniform (HW adds lane*16)
__device__ __forceinline__ void gl16(const u16* g, u16* l){
  __builtin_amdgcn_global_load_lds(
      (const __attribute__((address_space(1))) unsigned int*)g,
      (__attribute__((address_space(3))) unsigned int*)l, 16, 0, 0);
}

// ---------------- cast query fp32 -> bf16 ----------------
__global__ __launch_bounds__(256) void cast_qr(const float* __restrict__ in,
                                               u16* __restrict__ out){
  int i = blockIdx.x * 256 + threadIdx.x;      // 4 elems per thread
  float4 f = *(const float4*)(in + 4 * (size_t)i);
  u16 v[4] = { f2bf(f.x), f2bf(f.y), f2bf(f.z), f2bf(f.w) };
  *(uint2*)(out + 4 * (size_t)i) = *(const uint2*)v;
}

// ---------------- transpose + cast (fp32 R x C -> bf16 C x R) ----------------
__global__ __launch_bounds__(256) void transpose_cast(const float* __restrict__ in,
                                                      u16* __restrict__ out,
                                                      int R, int C){
  __shared__ float tile[32][33];
  int c0 = blockIdx.x * 32, r0 = blockIdx.y * 32;
  int tx = threadIdx.x, ty = threadIdx.y;
  #pragma unroll
  for (int i = 0; i < 32; i += 8)
    tile[ty + i][tx] = in[(size_t)(r0 + ty + i) * C + (c0 + tx)];
  __syncthreads();
  #pragma unroll
  for (int i = 0; i < 32; i += 8)
    out[(size_t)(c0 + ty + i) * R + (r0 + tx)] = f2bf(tile[tx][ty + i]);
}

// ---------------- [A] params = query @ Wp + bp  (128x128, swizzled LDS) -----
__global__ __launch_bounds__(256) void gemm_params(
    const u16* __restrict__ qrb,   // [3600][256] bf16
    const u16* __restrict__ WpT,   // [32768][256] bf16
    const float* __restrict__ bp,  // [32768] fp32
    u16* __restrict__ buf)         // [3600][32768] bf16
{
  __shared__ union SM {
    u16 AB[16384];     // As = [0,8192), Bs = [8192,16384)
    u16 C[128 * 136];  // epilogue stage (alias; used after final barrier)
  } sm;
  u16* As = sm.AB;
  u16* Bs = sm.AB + 8192;

  int n_base = blockIdx.x * 128;
  int m_base = blockIdx.y * 128;
  int t = threadIdx.x, wave = t >> 6, lane = t & 63, quad = lane >> 4, l15 = lane & 15;
  int mrow0 = (wave & 1) * 64, ncol0 = (wave >> 1) * 64;
  int srow = wave * 8 + (lane >> 3);              // staging row within 32-row band
  int scol = (((lane & 7) ^ (srow & 7)) * 8);     // swizzled fetch chunk (u16)
  int swz  = (quad ^ (l15 & 7)) * 8;              // read-side slot (u16), ks=0

  const f32x4 fz = {0.f, 0.f, 0.f, 0.f};
  f32x4 acc[4][4];
  #pragma unroll
  for (int i = 0; i < 4; i++)
    #pragma unroll
    for (int j = 0; j < 4; j++) acc[i][j] = fz;

  for (int ko = 0; ko < 4; ko++) {
    int k0 = ko * 64;
    #pragma unroll
    for (int i = 0; i < 4; i++) {
      int ar = m_base + i * 32 + srow; ar = ar < (BQT - 1) ? ar : (BQT - 1);
      gl16(qrb + (size_t)ar * KQ + k0 + scol, As + i * 2048 + wave * 512);
      int br = n_base + i * 32 + srow;
      gl16(WpT + (size_t)br * KQ + k0 + scol, Bs + i * 2048 + wave * 512);
    }
    __syncthreads();
    #pragma unroll
    for (int ks = 0; ks < 2; ks++) {
      int kf = ks ? (swz ^ 32) : swz;
      s16x8 a[4], b[4];
      #pragma unroll
      for (int i = 0; i < 4; i++)
        a[i] = *(const s16x8*)(As + (mrow0 + i * 16 + l15) * 64 + kf);
      #pragma unroll
      for (int j = 0; j < 4; j++)
        b[j] = *(const s16x8*)(Bs + (ncol0 + j * 16 + l15) * 64 + kf);
      #pragma unroll
      for (int i = 0; i < 4; i++)
        #pragma unroll
        for (int j = 0; j < 4; j++)
          acc[i][j] = __builtin_amdgcn_mfma_f32_16x16x32_bf16(a[i], b[j], acc[i][j], 0, 0, 0);
    }
    __syncthreads();
  }

  // acc (+bias) -> LDS, bf16, row stride 136 -> coalesced 16B stores
  #pragma unroll
  for (int j = 0; j < 4; j++) {
    int cl = ncol0 + j * 16 + l15;
    float bias = bp[n_base + cl];
    #pragma unroll
    for (int i = 0; i < 4; i++) {
      int rl = mrow0 + i * 16 + quad * 4;
      #pragma unroll
      for (int r = 0; r < 4; r++)
        sm.C[(rl + r) * 136 + cl] = f2bf(acc[i][j][r] + bias);
    }
  }
  __syncthreads();
  int c8 = (t & 15) * 8;
  #pragma unroll
  for (int it = 0; it < 8; it++) {
    int row = (t >> 4) + it * 16;
    int gr = m_base + row;
    s16x8 v = *(const s16x8*)(&sm.C[row * 136 + c8]);
    if (gr < BQT)
      *(s16x8*)(&buf[(size_t)gr * NP + n_base + c8]) = v;
  }
}

// ---------------- [B] per-(n,g) fused mixing (unchanged) ------------
#define MTSW(o, c) ((c) ^ ((((o) >> 3) & 7) * 8))
__global__ __launch_bounds__(256) void mixer(
    const float* __restrict__ x,  // [3600][4][32][64] fp32
    u16* __restrict__ buf)        // [3600][32768] bf16: params in / hidden out
{
  __shared__ u16 MT[64][72];
  __shared__ u16 H1[64][40];
  __shared__ u16 O2[128][72];
  __shared__ float redS[4], redQ[4];

  int bid = blockIdx.x;
  int nl = bid >> 2, g = bid & 3;
  int t = threadIdx.x, wave = t >> 6, lane = t & 63, quad = lane >> 4, l15 = lane & 15;
  u16* slice = buf + (size_t)nl * NP + g * TOTAL_T;
  const float* xs = x + ((size_t)nl * GQ + g) * (INP * EIN);

  s16x8 sfrag[2];
  #pragma unroll
  for (int mt = 0; mt < 2; mt++) {
    int qp = (wave * 2 + mt) * 16 + l15;
    sfrag[mt] = *(const s16x8*)(slice + MPAR + qp * INP + quad * 8);
  }
  s16x8 xfrag[2][2];
  #pragma unroll
  for (int nt = 0; nt < 2; nt++)
    #pragma unroll
    for (int ks = 0; ks < 2; ks++) {
      const float* src = xs + (nt * 16 + l15) * EIN + ks * 32 + quad * 8;
      float4 f0 = *(const float4*)(src);
      float4 f1 = *(const float4*)(src + 4);
      s16x8 v;
      v[0] = (short)f2bf(f0.x); v[1] = (short)f2bf(f0.y);
      v[2] = (short)f2bf(f0.z); v[3] = (short)f2bf(f0.w);
      v[4] = (short)f2bf(f1.x); v[5] = (short)f2bf(f1.y);
      v[6] = (short)f2bf(f1.z); v[7] = (short)f2bf(f1.w);
      xfrag[nt][ks] = v;
    }

  #pragma unroll
  for (int i = 0; i < 2; i++) {
    int ch = t + i * 256;
    int c = ch >> 3, o0 = (ch & 7) * 8;
    s16x8 v = *(const s16x8*)(slice + c * EOUT + o0);
    #pragma unroll
    for (int jj = 0; jj < 8; jj++) MT[o0 + jj][MTSW(o0 + jj, c)] = (u16)v[jj];
  }
  __syncthreads();

  const f32x4 fz = {0.f, 0.f, 0.f, 0.f};
  f32x4 acc1[2]; acc1[0] = fz; acc1[1] = fz;
  #pragma unroll
  for (int ks = 0; ks < 2; ks++) {
    int o = wave * 16 + l15;
    s16x8 a = *(const s16x8*)(&MT[o][MTSW(o, ks * 32 + quad * 8)]);
    acc1[0] = __builtin_amdgcn_mfma_f32_16x16x32_bf16(a, xfrag[0][ks], acc1[0], 0, 0, 0);
    acc1[1] = __builtin_amdgcn_mfma_f32_16x16x32_bf16(a, xfrag[1][ks], acc1[1], 0, 0, 0);
  }
  float s = 0.f, sq = 0.f;
  #pragma unroll
  for (int nt = 0; nt < 2; nt++)
    #pragma unroll
    for (int r = 0; r < 4; r++) { float v = acc1[nt][r]; s += v; sq += v * v; }
  #pragma unroll
  for (int off = 32; off >= 1; off >>= 1) { s += __shfl_xor(s, off); sq += __shfl_xor(sq, off); }
  if (lane == 0) { redS[wave] = s; redQ[wave] = sq; }
  __syncthreads();
  {
    float S1 = redS[0] + redS[1] + redS[2] + redS[3];
    float Q1 = redQ[0] + redQ[1] + redQ[2] + redQ[3];
    float mean = S1 * (1.f / 2048.f);
    float var = fmaxf(Q1 * (1.f / 2048.f) - mean * mean, 0.f);
    float rstd = rsqrtf(var + LN_EPS);
    #pragma unroll
    for (int nt = 0; nt < 2; nt++)
      #pragma unroll
      for (int r = 0; r < 4; r++) {
        float v = (acc1[nt][r] - mean) * rstd;
        v = v > 0.f ? v : 0.f;
        H1[wave * 16 + quad * 4 + r][nt * 16 + l15] = f2bf(v);
      }
  }
  __syncthreads();

  f32x4 acc2[2][4];
  #pragma unroll
  for (int mt = 0; mt < 2; mt++)
    #pragma unroll
    for (int nt = 0; nt < 4; nt++) acc2[mt][nt] = fz;
  #pragma unroll
  for (int nt = 0; nt < 4; nt++) {
    s16x8 b = *(const s16x8*)(&H1[nt * 16 + l15][quad * 8]);
    acc2[0][nt] = __builtin_amdgcn_mfma_f32_16x16x32_bf16(sfrag[0], b, acc2[0][nt], 0, 0, 0);
    acc2[1][nt] = __builtin_amdgcn_mfma_f32_16x16x32_bf16(sfrag[1], b, acc2[1][nt], 0, 0, 0);
  }
  s = 0.f; sq = 0.f;
  #pragma unroll
  for (int mt = 0; mt < 2; mt++)
    #pragma unroll
    for (int nt = 0; nt < 4; nt++)
      #pragma unroll
      for (int r = 0; r < 4; r++) { float v = acc2[mt][nt][r]; s += v; sq += v * v; }
  #pragma unroll
  for (int off = 32; off >= 1; off >>= 1) { s += __shfl_xor(s, off); sq += __shfl_xor(sq, off); }
  if (lane == 0) { redS[wave] = s; redQ[wave] = sq; }
  __syncthreads();
  {
    float S2 = redS[0] + redS[1] + redS[2] + redS[3];
    float Q2 = redQ[0] + redQ[1] + redQ[2] + redQ[3];
    float mean = S2 * (1.f / 8192.f);
    float var = fmaxf(Q2 * (1.f / 8192.f) - mean * mean, 0.f);
    float rstd = rsqrtf(var + LN_EPS);
    #pragma unroll
    for (int mt = 0; mt < 2; mt++)
      #pragma unroll
      for (int nt = 0; nt < 4; nt++)
        #pragma unroll
        for (int r = 0; r < 4; r++) {
          float v = (acc2[mt][nt][r] - mean) * rstd;
          v = v > 0.f ? v : 0.f;
          O2[(wave * 2 + mt) * 16 + quad * 4 + r][nt * 16 + l15] = f2bf(v);
        }
  }
  __syncthreads();
  #pragma unroll
  for (int i = 0; i < 4; i++) {
    int ch = t + i * 256;
    int qp = ch >> 3, o0 = (ch & 7) * 8;
    s16x8 v = *(const s16x8*)(&O2[qp][o0]);
    *(s16x8*)(slice + qp * EOUT + o0) = v;
  }
}

// ---------------- [C] out partials = hidden @ Wo (64x128, swizzled LDS) -----
__global__ __launch_bounds__(256) void gemm_out(
    const u16* __restrict__ hid,  // [3600][32768] bf16
    const u16* __restrict__ WoT,  // [256][32768] bf16
    float* __restrict__ part,     // [KS][3600][256] fp32
    int kslice)                   // K per split slice
{
  __shared__ u16 As[64 * 64];     // 8 KB
  __shared__ u16 Bs[128 * 64];    // 16 KB
  int n_base = blockIdx.x * 128;
  int m_base = blockIdx.y * 64;
  int ksl = blockIdx.z;
  int t = threadIdx.x, wave = t >> 6, lane = t & 63, quad = lane >> 4, l15 = lane & 15;
  int mrow0 = (wave & 1) * 32, ncol0 = (wave >> 1) * 64;
  int srow = wave * 8 + (lane >> 3);
  int scol = (((lane & 7) ^ (srow & 7)) * 8);     // swizzled fetch chunk (u16)
  int swz  = (quad ^ (l15 & 7)) * 8;              // read-side slot (u16), ks=0

  const f32x4 fz = {0.f, 0.f, 0.f, 0.f};
  f32x4 acc[2][4];
  #pragma unroll
  for (int i = 0; i < 2; i++)
    #pragma unroll
    for (int j = 0; j < 4; j++) acc[i][j] = fz;

  int kbase = ksl * kslice;
  for (int ko = 0; ko < kslice / 64; ko++) {
    int k0 = kbase + ko * 64;
    #pragma unroll
    for (int i = 0; i < 2; i++) {
      int ar = m_base + i * 32 + srow; ar = ar < (BQT - 1) ? ar : (BQT - 1);
      gl16(hid + (size_t)ar * NP + k0 + scol, As + i * 2048 + wave * 512);
    }
    #pragma unroll
    for (int i = 0; i < 4; i++) {
      int br = n_base + i * 32 + srow;
      gl16(WoT + (size_t)br * NP + k0 + scol, Bs + i * 2048 + wave * 512);
    }
    __syncthreads();
    #pragma unroll
    for (int ks = 0; ks < 2; ks++) {
      int kf = ks ? (swz ^ 32) : swz;
      s16x8 a[2], b[4];
      #pragma unroll
      for (int i = 0; i < 2; i++)
        a[i] = *(const s16x8*)(As + (mrow0 + i * 16 + l15) * 64 + kf);
      #pragma unroll
      for (int j = 0; j < 4; j++)
        b[j] = *(const s16x8*)(Bs + (ncol0 + j * 16 + l15) * 64 + kf);
      #pragma unroll
      for (int i = 0; i < 2; i++)
        #pragma unroll
        for (int j = 0; j < 4; j++)
          acc[i][j] = __builtin_amdgcn_mfma_f32_16x16x32_bf16(a[i], b[j], acc[i][j], 0, 0, 0);
    }
    __syncthreads();
  }
  #pragma unroll
  for (int j = 0; j < 4; j++) {
    int colg = n_base + ncol0 + j * 16 + l15;
    #pragma unroll
    for (int i = 0; i < 2; i++) {
      int row0 = m_base + mrow0 + i * 16 + quad * 4;
      #pragma unroll
      for (int r = 0; r < 4; r++)
        if (row0 + r < BQT)
          part[((size_t)ksl * BQT + row0 + r) * 256 + colg] = acc[i][j][r];
    }
  }
}

// ---------------- [R] reduce partials + bias + residual -> fp32 out --------
__global__ __launch_bounds__(256) void reduce_out(
    const float* __restrict__ part, const float* __restrict__ qr,
    const float* __restrict__ bo, float* __restrict__ out, int KS)
{
  int nl = blockIdx.x, j = threadIdx.x;
  float s = bo[j] + qr[(size_t)nl * KQ + j];
  for (int ks = 0; ks < KS; ks++)
    s += part[((size_t)ks * BQT + nl) * 256 + j];
  out[(size_t)nl * KQ + j] = s;
}

extern "C" void kernel_launch(void* const* d_in, const int* in_sizes, int n_in,
                              void* d_out, int out_size, void* d_ws, size_t ws_size,
                              hipStream_t stream)
{
  (void)in_sizes; (void)n_in; (void)out_size;
  const float* x  = (const float*)d_in[0];
  const float* qr = (const float*)d_in[1];
  const float* Wp = (const float*)d_in[2];
  const float* bp = (const float*)d_in[3];
  const float* Wo = (const float*)d_in[4];
  const float* bo = (const float*)d_in[5];
  float* out = (float*)d_out;

  char* ws = (char*)d_ws;
  u16* WpT = (u16*)ws;                          // 16 MiB
  u16* WoT = (u16*)(ws + 16777216);             // 16 MiB
  u16* buf = (u16*)(ws + 33554432);             // 3600*32768*2 = 225 MiB
  char* tail = ws + 33554432ull + (size_t)BQT * NP * 2ull;
  u16* qrb  = (u16*)tail;                       // 1.8 MB (dead after gemm_params)
  float* part = (float*)tail;                   // aliased: KS*3600*256*4

  size_t base = 33554432ull + (size_t)BQT * NP * 2ull;
  int KS = (ws_size >= base + 16ull * BQT * 256 * 4) ? 16 : 8;
  int kslice = NP / KS;

  cast_qr<<<dim3(BQT * KQ / 1024), 256, 0, stream>>>(qr, qrb);
  transpose_cast<<<dim3(NP / 32, KQ / 32), dim3(32, 8), 0, stream>>>(Wp, WpT, KQ, NP);
  transpose_cast<<<dim3(KQ / 32, NP / 32), dim3(32, 8), 0, stream>>>(Wo, WoT, NP, KQ);

  gemm_params<<<dim3(NP / 128, 29), 256, 0, stream>>>(qrb, WpT, bp, buf);
  mixer<<<dim3(BQT * GQ), 256, 0, stream>>>(x, buf);
  gemm_out<<<dim3(2, 57, KS), 256, 0, stream>>>(buf, WoT, part, kslice);
  reduce_out<<<dim3(BQT), 256, 0, stream>>>(part, qr, bo, out, KS);
}